// Round 9
// baseline (1325.533 us; speedup 1.0000x reference)
//
#include <hip/hip_runtime.h>
#include <math.h>

#define BB 16
#define SS 64
#define NN 128
#define FF 16
#define HH 64
#define EE 1024
#define ET 1152     // EE + NN self-loops
#define PSTRIDE 1160  // p row stride per graph (1152 + sentinel zeros)

__device__ __forceinline__ float readlane_f(float v, int k) {
  return __int_as_float(__builtin_amdgcn_readlane(__float_as_int(v), k));
}
__device__ __forceinline__ float sigmoidf_(float x) { return 1.f / (1.f + expf(-x)); }
__device__ __forceinline__ float sum4(float4 a) { return (a.x + a.y) + (a.z + a.w); }

// ---------------- CSR + padded-edge-list setup -------------------------------
// pad entry = edge_idx<<7 | src ; pads point at edge ET (p[g][ET] == 0).
__global__ void setup_csr_kernel(const int* __restrict__ ei,
                                 int* __restrict__ csrc,
                                 int* __restrict__ ctgt,
                                 int* __restrict__ plv,
                                 int* __restrict__ pad) {
  __shared__ int deg[NN], cur[NN], offs[NN + 1];
  __shared__ int PLs;
  int tid = threadIdx.x;
  if (tid < NN) deg[tid] = 0;
  __syncthreads();
  for (int e = tid; e < ET; e += 256) {
    int tg = (e < EE) ? ei[EE + e] : (e - EE);
    atomicAdd(&deg[tg], 1);
  }
  __syncthreads();
  if (tid == 0) {
    int s = 0;
    for (int i = 0; i < NN; ++i) { offs[i] = s; s += deg[i]; }
    offs[NN] = s;
    int m = 0;
    for (int i = 0; i < NN; ++i) m = max(m, deg[i]);
    m = (m + 7) & ~7;
    PLs = m;
    plv[0] = m;
  }
  __syncthreads();
  if (tid < NN) cur[tid] = offs[tid];
  __syncthreads();
  for (int e = tid; e < ET; e += 256) {
    int sv, tg;
    if (e < EE) { sv = ei[e]; tg = ei[EE + e]; }
    else        { sv = e - EE; tg = e - EE; }
    int pos = atomicAdd(&cur[tg], 1);
    csrc[pos] = sv;
    ctgt[pos] = tg;
  }
  __syncthreads();
  int PL = PLs;
  for (int idx = tid; idx < NN * PL; idx += 256) {
    int n2 = idx / PL, u = idx - n2 * PL;
    int o0 = offs[n2], dg = offs[n2 + 1] - o0;
    int e = o0 + u;
    pad[idx] = (u < dg) ? ((e << 7) | (csrc[e] & 127)) : (ET << 7);
  }
}

// ---------------- input projection: h = x @ W^T + b --------------------------
__global__ __launch_bounds__(256) void input_proj2_kernel(
    const float* __restrict__ x, const float* __restrict__ W,
    const float* __restrict__ bvec, float* __restrict__ h) {
  __shared__ __align__(16) float xs[128 * FF];   // 8 KB
  int tid = threadIdx.x, lane = tid & 63, wid = tid >> 6;
  size_t base = (size_t)blockIdx.x * (128 * FF);
  *(float4*)&xs[tid * 4]        = *(const float4*)(x + base + tid * 4);
  *(float4*)&xs[tid * 4 + 1024] = *(const float4*)(x + base + tid * 4 + 1024);
  float4 w4[FF / 4];
#pragma unroll
  for (int i = 0; i < FF / 4; ++i) w4[i] = ((const float4*)(W + lane * FF))[i];
  float bias = bvec[lane];
  __syncthreads();
  int r0 = wid * 32;
#pragma unroll 4
  for (int r = r0; r < r0 + 32; ++r) {
    const float4* xr = (const float4*)&xs[r * FF];   // LDS broadcast
    float4 a = {bias, 0.f, 0.f, 0.f};
#pragma unroll
    for (int f = 0; f < FF / 4; ++f) a += xr[f] * w4[f];
    h[(size_t)blockIdx.x * (128 * HH) + (size_t)r * HH + lane] = sum4(a);
  }
}

// ---------------- GAT-A: xl/xr projection GEMM, high occupancy ---------------
// Block = 4 waves over 64 h-rows staged in 16 KB LDS (coalesced in).
// wave 0: xl rows 0-31, wave 1: xl rows 32-63, wave 2/3: xr likewise.
// Per-lane weight row in VGPRs; h rows are same-address b128 LDS broadcasts.
// No launch-bounds cap: VGPR ~80, LDS 16 KB -> ~6 blocks/CU (24 waves).
__global__ __launch_bounds__(256) void xlxr_gemm_kernel(
    const float* __restrict__ hin,
    const float* __restrict__ Wl, const float* __restrict__ bl,
    const float* __restrict__ Wr, const float* __restrict__ br,
    float* __restrict__ xl, float* __restrict__ xr) {
  __shared__ __align__(16) float hs[64 * HH];      // 16 KB
  int tid = threadIdx.x, lane = tid & 63, wid = tid >> 6;
  size_t base = (size_t)blockIdx.x * (64 * HH);
  // stage 64 rows coalesced (4 float4 per thread)
#pragma unroll
  for (int i = 0; i < 4; ++i)
    *(float4*)&hs[(tid + i * 256) * 4] = *(const float4*)(hin + base + (tid + i * 256) * 4);
  int half = wid >> 1;                             // 0 -> xl, 1 -> xr
  const float* W  = half ? Wr : Wl;
  const float* bv = half ? br : bl;
  float* outp     = half ? xr : xl;
  float4 w4[HH / 4];
#pragma unroll
  for (int i = 0; i < HH / 4; ++i) w4[i] = ((const float4*)(W + lane * HH))[i];
  float bias = bv[lane];
  __syncthreads();
  int r0 = (wid & 1) * 32;
#pragma unroll 2
  for (int r = r0; r < r0 + 32; ++r) {
    const float4* hr = (const float4*)&hs[r * HH];  // broadcast
    float4 a = {bias, 0.f, 0.f, 0.f};
#pragma unroll
    for (int k = 0; k < HH / 4; ++k) a += hr[k] * w4[k];
    outp[base + (size_t)r * HH + lane] = sum4(a);
  }
}

// ---------------- GAT-B: thread-per-edge logits, zero LDS --------------------
// grid = (9, BB*SS); 128 threads; e_local = bx*128+tid in [0,1152).
// Reads xl[src] / xr[tgt] rows from L2 (written by GAT-A moments before).
__global__ __launch_bounds__(128) void edge_logit_kernel(
    const float* __restrict__ xl, const float* __restrict__ xr,
    const int* __restrict__ csr_src, const int* __restrict__ csr_tgt,
    const float* __restrict__ att, float* __restrict__ p) {
  int tid = threadIdx.x;
  int el = blockIdx.x * 128 + tid;     // < 1152 exactly
  int g = blockIdx.y;
  int s = csr_src[el], t = csr_tgt[el];
  const float4* xlr = (const float4*)(xl + ((size_t)g * NN + s) * HH);
  const float4* xrr = (const float4*)(xr + ((size_t)g * NN + t) * HH);
  float4 a = {0.f, 0.f, 0.f, 0.f};
#pragma unroll
  for (int k = 0; k < HH / 4; ++k) {
    float4 v = xlr[k] + xrr[k];
    v.x = fmaxf(v.x, 0.2f * v.x);
    v.y = fmaxf(v.y, 0.2f * v.y);
    v.z = fmaxf(v.z, 0.2f * v.z);
    v.w = fmaxf(v.w, 0.2f * v.w);
    float4 at = ((const float4*)att)[k];   // uniform -> scalar
    a += v * at;
  }
  p[(size_t)g * PSTRIDE + el] = expf(sum4(a));   // no max-sub (validated R5-R8)
  if (blockIdx.x == 0 && tid < 8) p[(size_t)g * PSTRIDE + ET + tid] = 0.f;  // sentinel
}

// ---------------- GAT-C: gather, zero LDS, batch-8 pad list ------------------
// Block = graph (b,s), 4 waves; wave w owns nodes w, w+4, ... Per edge:
// p via uniform s_load (L2), xl column via ONE coalesced 256B global read
// (L2-hot). 8 independent edges in flight. Writes h in place (reads only
// xl/p, so no hazard).
__global__ __launch_bounds__(256) void gather_kernel(
    const float* __restrict__ xl, const float* __restrict__ p,
    const int* __restrict__ plv, const int* __restrict__ pad,
    const float* __restrict__ bo, float* __restrict__ hout) {
  int tid = threadIdx.x, lane = tid & 63, wid = tid >> 6;
  int g = blockIdx.x;
  const float* pg = p + (size_t)g * PSTRIDE;
  const float* xg = xl + (size_t)g * (NN * HH);
  float bo_l = bo[lane];
  int PL = plv[0];                     // uniform
#pragma unroll 1
  for (int n = wid; n < NN; n += 4) {
    const int* pl = pad + n * PL;      // wave-uniform -> s_loads
    float acc = 0.f, z = 0.f;
#pragma unroll 1
    for (int i = 0; i < PL; i += 8) {
      int st[8];
#pragma unroll
      for (int u = 0; u < 8; ++u) st[u] = pl[i + u];
      float pv[8], xv[8];
#pragma unroll
      for (int u = 0; u < 8; ++u) {
        pv[u] = pg[st[u] >> 7];                         // uniform (sentinel->0)
        xv[u] = xg[(st[u] & 127) * HH + lane];          // coalesced 256B
      }
#pragma unroll
      for (int u = 0; u < 8; ++u) { acc = fmaf(pv[u], xv[u], acc); z += pv[u]; }
    }
    hout[((size_t)g * NN + n) * HH + lane] = fmaxf(acc / z + bo_l, 0.f);
  }
}

// ---------------- GRU: producer-consumer (R4 structure, measured 210 us) -----
// Only change vs R4: __launch_bounds__(128, 4) -> 16 waves/CU (R4's (128,2)
// capped residency at 8 waves/CU despite VGPR=112; latency-bound at 55% VALU).
__global__ __launch_bounds__(128, 4) void gru_pc_kernel(
    const float* __restrict__ hbuf,
    const float* __restrict__ Wih, const float* __restrict__ Whh,
    const float* __restrict__ bih, const float* __restrict__ bhh,
    const float* __restrict__ oW1, const float* __restrict__ ob1,
    const float* __restrict__ oW2, const float* __restrict__ ob2,
    const float* __restrict__ dW1, const float* __restrict__ db1,
    const float* __restrict__ dW2, const float* __restrict__ db2,
    float* __restrict__ out) {
  int lane = threadIdx.x & 63;
  int w = (int)threadIdx.x >> 6;     // 0 = producer (ih), 1 = consumer (hh)
  int seq = blockIdx.x;              // b*N + n
  int b = seq >> 7, n = seq & (NN - 1);

  __shared__ float ring[2][3][HH];
  __shared__ float hsh[HH];

  const float* Wsel = w ? Whh : Wih;
  const float* Bsel = w ? bhh : bih;
  float wt[3][HH];
#pragma unroll
  for (int g = 0; g < 3; ++g) {
    const float4* src = (const float4*)(Wsel + (size_t)(g * 64 + lane) * HH);
#pragma unroll
    for (int i = 0; i < HH / 4; ++i)
      *(float4*)&wt[g][4 * i] = src[i];
  }
  float b_r = Bsel[lane], b_z = Bsel[64 + lane], b_n = Bsel[128 + lane];

  const float* xbase = hbuf + ((size_t)(b * SS) * NN + n) * HH;
  float hj = 0.f;

  if (w == 0) {
    float xv = xbase[lane];
    float ar0 = b_r, ar1 = 0.f, az0 = b_z, az1 = 0.f, an0 = b_n, an1 = 0.f;
#pragma unroll
    for (int k = 0; k < HH; k += 2) {
      float x0 = readlane_f(xv, k), x1 = readlane_f(xv, k + 1);
      ar0 += x0 * wt[0][k];     az0 += x0 * wt[1][k];     an0 += x0 * wt[2][k];
      ar1 += x1 * wt[0][k + 1]; az1 += x1 * wt[1][k + 1]; an1 += x1 * wt[2][k + 1];
    }
    ring[0][0][lane] = ar0 + ar1;
    ring[0][1][lane] = az0 + az1;
    ring[0][2][lane] = an0 + an1;
  }
  __syncthreads();

#pragma unroll 1
  for (int t = 0; t < SS; ++t) {
    if (w == 0) {
      if (t + 1 < SS) {
        const float* xr = xbase + (size_t)(t + 1) * NN * HH;
        float xv = xr[lane];
        float ar0 = b_r, ar1 = 0.f, az0 = b_z, az1 = 0.f, an0 = b_n, an1 = 0.f;
#pragma unroll
        for (int k = 0; k < HH; k += 2) {
          float x0 = readlane_f(xv, k), x1 = readlane_f(xv, k + 1);
          ar0 += x0 * wt[0][k];     az0 += x0 * wt[1][k];     an0 += x0 * wt[2][k];
          ar1 += x1 * wt[0][k + 1]; az1 += x1 * wt[1][k + 1]; an1 += x1 * wt[2][k + 1];
        }
        int slot = (t + 1) & 1;
        ring[slot][0][lane] = ar0 + ar1;
        ring[slot][1][lane] = az0 + az1;
        ring[slot][2][lane] = an0 + an1;
      }
    } else {
      int slot = t & 1;
      float gir = ring[slot][0][lane];
      float giz = ring[slot][1][lane];
      float gin = ring[slot][2][lane];
      float ar0 = b_r, ar1 = 0.f, az0 = b_z, az1 = 0.f, an0 = b_n, an1 = 0.f;
#pragma unroll
      for (int k = 0; k < HH; k += 2) {
        float h0 = readlane_f(hj, k), h1 = readlane_f(hj, k + 1);
        ar0 += h0 * wt[0][k];     az0 += h0 * wt[1][k];     an0 += h0 * wt[2][k];
        ar1 += h1 * wt[0][k + 1]; az1 += h1 * wt[1][k + 1]; an1 += h1 * wt[2][k + 1];
      }
      float ghr = ar0 + ar1, ghz = az0 + az1, ghn = an0 + an1;
      float rg = sigmoidf_(gir + ghr);
      float zg = sigmoidf_(giz + ghz);
      float ng = tanhf(gin + rg * ghn);
      hj = (1.f - zg) * ng + zg * hj;
    }
    __syncthreads();
  }

  if (w == 1) hsh[lane] = hj;
  __syncthreads();

  if (w == 1) {
    int half = lane >> 5, jp = lane & 31;
    const float* W1 = half ? dW1 : oW1;
    const float* b1 = half ? db1 : ob1;
    const float* W2 = half ? dW2 : oW2;
    const float* b2 = half ? db2 : ob2;
    float wv[HH];
#pragma unroll
    for (int i = 0; i < HH / 4; ++i)
      *(float4*)&wv[4 * i] = ((const float4*)(W1 + jp * HH))[i];
    float acc = b1[jp];
#pragma unroll
    for (int k = 0; k < HH; k += 4) {
      float4 hb = *(const float4*)(hsh + k);
      acc += hb.x * wv[k + 0];
      acc += hb.y * wv[k + 1];
      acc += hb.z * wv[k + 2];
      acc += hb.w * wv[k + 3];
    }
    float val = fmaxf(acc, 0.f) * W2[jp];
    val += __shfl_down(val, 16, 32);
    val += __shfl_down(val, 8, 32);
    val += __shfl_down(val, 4, 32);
    val += __shfl_down(val, 2, 32);
    val += __shfl_down(val, 1, 32);
    if (jp == 0) out[half * (BB * NN) + seq] = val + b2[0];
  }
}

// ---------------- launch -----------------------------------------------------
extern "C" void kernel_launch(void* const* d_in, const int* in_sizes, int n_in,
                              void* d_out, int out_size, void* d_ws, size_t ws_size,
                              hipStream_t stream) {
  const float* x       = (const float*)d_in[0];
  const int*   ei      = (const int*)d_in[1];
  const float* in_W    = (const float*)d_in[2];
  const float* in_b    = (const float*)d_in[3];
  const float* gat_Wl  = (const float*)d_in[4];
  const float* gat_bl  = (const float*)d_in[5];
  const float* gat_Wr  = (const float*)d_in[6];
  const float* gat_br  = (const float*)d_in[7];
  const float* gat_att = (const float*)d_in[8];
  const float* gat_bias= (const float*)d_in[9];
  const float* gru_Wih = (const float*)d_in[10];
  const float* gru_Whh = (const float*)d_in[11];
  const float* gru_bih = (const float*)d_in[12];
  const float* gru_bhh = (const float*)d_in[13];
  const float* oh_W1   = (const float*)d_in[14];
  const float* oh_b1   = (const float*)d_in[15];
  const float* oh_W2   = (const float*)d_in[16];
  const float* oh_b2   = (const float*)d_in[17];
  const float* dh_W1   = (const float*)d_in[18];
  const float* dh_b1   = (const float*)d_in[19];
  const float* dh_W2   = (const float*)d_in[20];
  const float* dh_b2   = (const float*)d_in[21];
  float* out = (float*)d_out;

  char* ws = (char*)d_ws;
  size_t hfloats = (size_t)BB * SS * NN * HH;        // 8.39 M floats (33.5 MB)
  float* hbuf = (float*)ws;
  float* xlbuf = hbuf + hfloats;                     // 33.5 MB
  float* xrbuf = xlbuf + hfloats;                    // 33.5 MB
  float* pbuf  = xrbuf + hfloats;                    // 1024*1160*4 = 4.75 MB
  int* csr_src = (int*)(pbuf + (size_t)BB * SS * PSTRIDE);
  int* csr_tgt = csr_src + ET;
  int* plv     = csr_tgt + ET;
  int* pad     = plv + 8;                            // <= NN*256 ints

  int NROWS = BB * SS * NN;                          // 131072

  setup_csr_kernel<<<1, 256, 0, stream>>>(ei, csr_src, csr_tgt, plv, pad);
  input_proj2_kernel<<<NROWS / 128, 256, 0, stream>>>(x, in_W, in_b, hbuf);
  for (int l = 0; l < 2; ++l) {
    xlxr_gemm_kernel<<<NROWS / 64, 256, 0, stream>>>(
        hbuf, gat_Wl + l * HH * HH, gat_bl + l * HH,
        gat_Wr + l * HH * HH, gat_br + l * HH, xlbuf, xrbuf);
    edge_logit_kernel<<<dim3(9, BB * SS), 128, 0, stream>>>(
        xlbuf, xrbuf, csr_src, csr_tgt, gat_att + l * HH, pbuf);
    gather_kernel<<<BB * SS, 256, 0, stream>>>(
        xlbuf, pbuf, plv, pad, gat_bias + l * HH, hbuf);
  }
  gru_pc_kernel<<<BB * NN, 128, 0, stream>>>(
      hbuf, gru_Wih, gru_Whh, gru_bih, gru_bhh,
      oh_W1, oh_b1, oh_W2, oh_b2, dh_W1, dh_b1, dh_W2, dh_b2, out);
}